// Round 17
// baseline (195.722 us; speedup 1.0000x reference)
//
#include <hip/hip_runtime.h>
#include <stdint.h>

#define B_SZ 32
#define T_SZ 300
#define F_IN 3072
#define F_HID 410
#define F_OUT 10
#define M_SZ (B_SZ * T_SZ)              // 9600
#define N_PAD 448                       // a1 row stride = gemm1 N (7 x 64)
#define A2_STRIDE 16
#define SB2_STRIDE 16                   // spike-bit words per m (14 used)
#define NCHUNK 10
#define CLEN 30
#define NKB (F_IN / 256)                // 12 K-blocks of 256
#define MT2 (M_SZ / 128)                // 75 128-row gemm tiles
#define W1_BLOCKS 672                   // 448*3072/8/256
#define RNG_BLOCKS 14400                // 921600*4/256 (4 threads/word, 8 bits each)

// f32(exp(f32(-0.1))) — PSP decay, matches XLA's correctly-rounded exp
#define DECAY 0.90483741803595957f
#define THETA 10.0f
#define KS2 (0x1BD11BDAu ^ 42u)

typedef __attribute__((ext_vector_type(8))) int i32x8;
typedef __attribute__((ext_vector_type(16))) float f32x16;

// FORCED single-instruction rotate-left, in-place. v_alignbit_b32 x,x,x,(32-r)
// = rotl(r). (R3: prep is at the sustainable VALU issue floor.)
#define TF_R(r) { x0 += x1; \
  asm("v_alignbit_b32 %0, %0, %0, %1" : "+v"(x1) : "n"(32 - (r))); \
  x1 ^= x0; }

// JAX partitionable threefry2x32, key=(0,42), ctr=(0, x1i-42). x0 key-add is 0
// (elided); x1 key-add folded into caller's x1i = base + 42 + jj. Returns o0^o1.
__device__ __forceinline__ uint32_t tf_bits(uint32_t x1i) {
  uint32_t x0 = 0u, x1 = x1i;
  TF_R(13) TF_R(15) TF_R(26) TF_R(6)
  x0 += 42u; x1 += KS2 + 1u;
  TF_R(17) TF_R(29) TF_R(16) TF_R(24)
  x0 += KS2; x1 += 2u;
  TF_R(13) TF_R(15) TF_R(26) TF_R(6)
  x1 += 42u + 3u;
  TF_R(17) TF_R(29) TF_R(16) TF_R(24)
  x0 += 42u; x1 += KS2 + 4u;
  TF_R(13) TF_R(15) TF_R(26) TF_R(6)
  x0 += KS2; x1 += 5u;
  return x0 ^ x1;
}

// async global->LDS, 16 B per lane; LDS dest = wave-uniform base + lane*16
__device__ __forceinline__ void gld16(const void* g, void* l) {
  __builtin_amdgcn_global_load_lds(
      (const __attribute__((address_space(1))) uint32_t*)g,
      (__attribute__((address_space(3))) uint32_t*)l, 16, 0, 0);
}

// R17 MEASUREMENT ROUND: R13 baseline, but scan_spike/gemm2/psp2 (all
// idempotent: re-read unchanged inputs, rewrite identical outputs) launched
// 3x each. Delta vs R13 = 2*(s+G+P) + ~6us gaps. This both sizes the trio
// (R16 ledger says 76-80us; issue models say 12-16) AND tests whether the
// harness's 44.7us fillBufferAligned workspace-poison executes inside the
// timed region (R15 top-5 showed it interleaved; R8's anomalous total
// reconciles only under that hypothesis).

// Merged prep (R4/R7-verified, unchanged).
__global__ __launch_bounds__(256) void prep(const float* __restrict__ inp,
                                            const float* __restrict__ W1,
                                            uint8_t* __restrict__ W1s,
                                            uint32_t* __restrict__ sbitsT) {
  if (blockIdx.x < W1_BLOCKS) {
    int idx = blockIdx.x * 256 + threadIdx.x;
    int g = idx * 8;
    int n = g / F_IN;
    int k = g - n * F_IN;
    uint32_t d0 = 0u, d1 = 0u;
    if (n < F_HID) {
      const float* s = W1 + (size_t)n * F_IN + k;
      float4 v0 = ((const float4*)s)[0];
      float4 v1 = ((const float4*)s)[1];
      int t0 = __builtin_amdgcn_cvt_pk_fp8_f32(v0.x, v0.y, 0, false);
      t0 = __builtin_amdgcn_cvt_pk_fp8_f32(v0.z, v0.w, t0, true);
      int t1 = __builtin_amdgcn_cvt_pk_fp8_f32(v1.x, v1.y, 0, false);
      t1 = __builtin_amdgcn_cvt_pk_fp8_f32(v1.z, v1.w, t1, true);
      d0 = (uint32_t)t0; d1 = (uint32_t)t1;
    }
    int nt = n >> 6, r = n & 63;
    int kb = k >> 8, c = (k >> 4) & 15, half = (k >> 3) & 1;
    size_t dst = ((((size_t)nt * NKB + kb) * 64 + r) * 16 + (c ^ (r & 15))) * 16 + half * 8;
    *(uint2*)(W1s + dst) = make_uint2(d0, d1);
  } else {
    uint32_t idx = (blockIdx.x - W1_BLOCKS) * 256u + threadIdx.x;  // [0, 3686400)
    uint32_t q = idx & 3u;          // byte within word
    uint32_t j = idx >> 2;          // word index [0, 921600)
    uint32_t r = j & 63u;
    uint32_t t1 = j >> 6;
    uint32_t wi = t1 & 7u;
    uint32_t t2 = t1 >> 3;          // (mt*12 + kb) in [0, 1800)
    uint32_t kb = t2 % (uint32_t)NKB;
    uint32_t mt = t2 / (uint32_t)NKB;
    uint32_t m = mt * 64u + r;      // GEMM row = b*300 + t
    uint32_t b = m / (uint32_t)T_SZ;
    uint32_t f = (kb * 8u + wi) * 32u + q * 8u;
    const float* p = inp + b * F_IN + f;
    float4 va = ((const float4*)p)[0];
    float4 vb = ((const float4*)p)[1];
    uint32_t T0 = (uint32_t)ceilf(va.x * 8388608.0f);
    uint32_t T1 = (uint32_t)ceilf(va.y * 8388608.0f);
    uint32_t T2 = (uint32_t)ceilf(va.z * 8388608.0f);
    uint32_t T3 = (uint32_t)ceilf(va.w * 8388608.0f);
    uint32_t T4 = (uint32_t)ceilf(vb.x * 8388608.0f);
    uint32_t T5 = (uint32_t)ceilf(vb.y * 8388608.0f);
    uint32_t T6 = (uint32_t)ceilf(vb.z * 8388608.0f);
    uint32_t T7 = (uint32_t)ceilf(vb.w * 8388608.0f);
    uint32_t b42 = m * (uint32_t)F_IN + f + 42u;   // counter base + key lo
    uint32_t w = 0u;
#define GEN(jj, Tn) { uint32_t bits = tf_bits(b42 + (jj)); \
  w |= ((bits >> 9) < (Tn)) ? (1u << (jj)) : 0u; }
    GEN(0, T0) GEN(1, T1) GEN(2, T2) GEN(3, T3)
    GEN(4, T4) GEN(5, T5) GEN(6, T6) GEN(7, T7)
#undef GEN
    ((uint8_t*)sbitsT)[idx] = (uint8_t)w;   // byte q of word j: bits [8q, 8q+8)
  }
}

// R13 gemm1 (verified, kept): BM=128, BN=64, grid 75x7, 4 waves, 2 MFMAs per
// A-expand, nontemporal stores, counted-vmcnt 2-deep pipeline. Measured R16:
// ~19.6us.
__global__ __launch_bounds__(256) void gemm1(const uint32_t* __restrict__ sbitsT,
                                             const uint8_t* __restrict__ W1s,
                                             float* __restrict__ a1) {
  __shared__ uint32_t sAT[2][2][512];   // [buf][64-row half][wi*64+row] 8 KB
  __shared__ uint8_t sB[2][64 * 256];   // [buf] swizzled image, 32 KB

  const int tid = threadIdx.x;
  const int bx = blockIdx.x;            // 128-row tile [0,75)
  const int nt = blockIdx.y;
  const int m0 = bx * 128;
  const int n0 = nt * 64;
  const int wv = tid >> 6, lane = tid & 63;
  const int wm = wv * 32;               // wave's row strip in [0,128)
  const int half = wv >> 1;             // which 64-row mtile
  const int lrow = (wv & 1) * 32;       // strip base within the half
  const int l31 = lane & 31, lh = lane >> 5;

  const uint8_t* gB0 = W1s + (size_t)nt * NKB * 16384;
  const uint8_t* gA0 = (const uint8_t*)sbitsT + (size_t)(2 * bx) * NKB * 2048;

  auto STAGE = [&](int buf, int kb) {   // exactly 5 gld16 per wave
    const uint8_t* gB = gB0 + (size_t)kb * 16384;
#pragma unroll
    for (int q = 0; q < 4; ++q)
      gld16(gB + (wv * 4 + q) * 1024 + lane * 16, &sB[buf][(wv * 4 + q) * 1024]);
    gld16(gA0 + (size_t)half * NKB * 2048 + (size_t)kb * 2048 + (wv & 1) * 1024 + lane * 16,
          (uint8_t*)&sAT[buf][half][0] + (wv & 1) * 1024);
  };

  f32x16 acc0, acc1;
#pragma unroll
  for (int e = 0; e < 16; ++e) { acc0[e] = 0.0f; acc1[e] = 0.0f; }

  auto COMPUTE = [&](int buf) {
    const uint8_t* sBc = sB[buf];
    const uint32_t* sATc = &sAT[buf][half][0];
#pragma unroll
    for (int sub = 0; sub < 4; ++sub) {
      int cb = sub * 4 + lh * 2;
      int r0 = l31, r1 = 32 + l31;
      uint4 a0 = *(uint4*)&sBc[r0 * 256 + (((cb + 0) ^ (r0 & 15)) << 4)];
      uint4 a1v = *(uint4*)&sBc[r0 * 256 + (((cb + 1) ^ (r0 & 15)) << 4)];
      uint4 b0 = *(uint4*)&sBc[r1 * 256 + (((cb + 0) ^ (r1 & 15)) << 4)];
      uint4 b1 = *(uint4*)&sBc[r1 * 256 + (((cb + 1) ^ (r1 & 15)) << 4)];
      i32x8 bfr0, bfr1;
      bfr0[0] = a0.x; bfr0[1] = a0.y; bfr0[2] = a0.z; bfr0[3] = a0.w;
      bfr0[4] = a1v.x; bfr0[5] = a1v.y; bfr0[6] = a1v.z; bfr0[7] = a1v.w;
      bfr1[0] = b0.x; bfr1[1] = b0.y; bfr1[2] = b0.z; bfr1[3] = b0.w;
      bfr1[4] = b1.x; bfr1[5] = b1.y; bfr1[6] = b1.z; bfr1[7] = b1.w;
      uint32_t w = sATc[(sub * 2 + lh) * 64 + lrow + l31];
      i32x8 afr;
#pragma unroll
      for (int j = 0; j < 8; ++j) {
        uint32_t n = (w >> (4 * j)) & 15u;
        afr[j] = (int)(((n * 0x204081u) & 0x01010101u) * 0x38u);
      }
      acc0 = __builtin_amdgcn_mfma_scale_f32_32x32x64_f8f6f4(
          afr, bfr0, acc0, 0, 0, 0, 127, 0, 127);
      acc1 = __builtin_amdgcn_mfma_scale_f32_32x32x64_f8f6f4(
          afr, bfr1, acc1, 0, 0, 0, 127, 0, 127);
    }
  };

  // 2-deep prologue: tiles 0,1 in flight (10 loads/wave)
  STAGE(0, 0);
  STAGE(1, 1);
  int cur = 0;
  for (int kb = 0; kb < NKB - 1; ++kb) {
    asm volatile("s_waitcnt vmcnt(5)" ::: "memory");
    __builtin_amdgcn_s_barrier();
    __builtin_amdgcn_sched_barrier(0);
    COMPUTE(cur);
    __builtin_amdgcn_sched_barrier(0);
    __builtin_amdgcn_s_barrier();      // all waves done reading buf[cur]
    if (kb < NKB - 2) STAGE(cur, kb + 2);
    cur ^= 1;
  }
  asm volatile("s_waitcnt vmcnt(0)" ::: "memory");
  __builtin_amdgcn_s_barrier();
  __builtin_amdgcn_sched_barrier(0);
  COMPUTE(cur);                        // last tile

#pragma unroll
  for (int rg = 0; rg < 16; ++rg) {
    int row = m0 + wm + (rg & 3) + 8 * (rg >> 2) + 4 * lh;
    __builtin_nontemporal_store(acc0[rg], &a1[(size_t)row * N_PAD + n0 + l31]);
    __builtin_nontemporal_store(acc1[rg], &a1[(size_t)row * N_PAD + n0 + 32 + l31]);
  }
}

// R7-verified: psp1 + fscan + threshold merged, no partial materialization.
__global__ __launch_bounds__(640) void scan_spike(const float* __restrict__ a1,
                                                  uint32_t* __restrict__ sb2) {
  __shared__ float fin_s[NCHUNK][64];
  const int oblk = blockIdx.x;          // [0,7)
  const int b = blockIdx.y;             // [0,32)
  const int c = threadIdx.x >> 6;       // chunk = wave id
  const int lane = threadIdx.x & 63;
  const int o = oblk * 64 + lane;
  const float* p = a1 + ((size_t)(b * T_SZ + c * CLEN)) * N_PAD + o;
  float pa[CLEN];
  float u = 0.0f;
#pragma unroll
  for (int i = 0; i < CLEN; ++i) {
    u = __fadd_rn(__fmul_rn(DECAY, u), p[(size_t)i * N_PAD]);
    pa[i] = u;
  }
  fin_s[c][lane] = u;
  __syncthreads();
  float d30 = 1.0f;
#pragma unroll
  for (int i = 0; i < CLEN; ++i) d30 *= DECAY;
  float F = 0.0f;
  for (int cc = 0; cc < c; ++cc)        // fscan's exact chain: F = v + d30*F
    F = fin_s[cc][lane] + d30 * F;
  float dp = DECAY;                     // DECAY^(tl+1), ag2's exact sequence
  const int m0 = b * T_SZ + c * CLEN;
#pragma unroll
  for (int i = 0; i < CLEN; ++i) {
    float uu = (c > 0) ? __fadd_rn(pa[i], __fmul_rn(dp, F)) : pa[i];
    unsigned long long msk = __ballot(uu >= THETA);
    if (lane == 0)
      *(uint2*)&sb2[(size_t)(m0 + i) * SB2_STRIDE + oblk * 2] =
          make_uint2((uint32_t)msk, (uint32_t)(msk >> 32));
    dp *= DECAY;
  }
}

// R7-verified: layer-2 GEMM from spike bits.
__global__ __launch_bounds__(256) void gemm2(const uint32_t* __restrict__ sb2,
                                             const float* __restrict__ W2,
                                             float* __restrict__ a2) {
  __shared__ float sW2[F_OUT * F_HID];   // 16.4 KB
  for (int i = threadIdx.x; i < F_OUT * F_HID; i += 256) sW2[i] = W2[i];
  __syncthreads();
  int m = blockIdx.x * 4 + (threadIdx.x >> 6);
  int lane = threadIdx.x & 63;
  int lh = lane >> 5;
  float p[F_OUT];
#pragma unroll
  for (int o = 0; o < F_OUT; ++o) p[o] = 0.0f;
#pragma unroll
  for (int j = 0; j < 7; ++j) {
    int hh = lane + j * 64;
    uint32_t w = sb2[(size_t)m * SB2_STRIDE + j * 2 + lh];
    float s = (float)((w >> (lane & 31)) & 1u);   // 0 for hh>=F_HID by construction
    int hcl = hh < F_HID ? hh : 0;
#pragma unroll
    for (int o = 0; o < F_OUT; ++o) p[o] = fmaf(s, sW2[o * F_HID + hcl], p[o]);
  }
#pragma unroll
  for (int o = 0; o < F_OUT; ++o)
#pragma unroll
    for (int s = 1; s < 64; s <<= 1) p[o] += __shfl_xor(p[o], s, 64);
  if (lane < F_OUT) a2[(size_t)m * A2_STRIDE + lane] = p[lane];
}

// Layer-2 PSP, chunked, one block per batch; lanes (o,c) in [10x10].
__global__ __launch_bounds__(128) void psp2(const float* __restrict__ a2,
                                            float* __restrict__ out) {
  __shared__ float chf[NCHUNK][F_OUT];
  __shared__ float seed[NCHUNK][F_OUT];
  int b = blockIdx.x;
  int tid = threadIdx.x;
  int o = tid / NCHUNK, c = tid % NCHUNK;
  const float* p = a2 + ((size_t)(b * T_SZ + c * CLEN)) * A2_STRIDE + o;
  float v[CLEN];
  float pa[CLEN];
  if (tid < F_OUT * NCHUNK) {
#pragma unroll
    for (int i = 0; i < CLEN; ++i) v[i] = p[(size_t)i * A2_STRIDE];
    float u = 0.0f;
#pragma unroll
    for (int i = 0; i < CLEN; ++i) {
      u = __fadd_rn(__fmul_rn(DECAY, u), v[i]);
      pa[i] = u;
    }
    chf[c][o] = u;
  }
  __syncthreads();
  if (tid < F_OUT) {
    float d30 = 1.0f;
#pragma unroll
    for (int i = 0; i < CLEN; ++i) d30 *= DECAY;
    float F = 0.0f;
    for (int cc = 0; cc < NCHUNK; ++cc) {
      F = chf[cc][tid] + d30 * F;
      seed[cc][tid] = F;
    }
  }
  __syncthreads();
  if (tid < F_OUT * NCHUNK) {
    float F = (c == 0) ? 0.0f : seed[c - 1][o];
    float dp = DECAY;
    float* q = out + (size_t)b * F_OUT * T_SZ + (size_t)o * T_SZ + c * CLEN;
#pragma unroll
    for (int i = 0; i < CLEN; ++i) {
      float u = (c == 0) ? pa[i] : __fadd_rn(pa[i], __fmul_rn(dp, F));
      q[i] = (u >= THETA) ? 1.0f : 0.0f;
      dp *= DECAY;
    }
  }
}

extern "C" void kernel_launch(void* const* d_in, const int* in_sizes, int n_in,
                              void* d_out, int out_size, void* d_ws, size_t ws_size,
                              hipStream_t stream) {
  const float* inp = (const float*)d_in[0];  // [32,3,32,32]
  const float* W1  = (const float*)d_in[1];  // [410,3072]
  const float* W2  = (const float*)d_in[2];  // [10,410]
  float* out = (float*)d_out;                // [32,10,300]
  char* ws = (char*)d_ws;
  // ws: W1s 1376256 | sbitsT 3686400 | a1 17203200 | sb2 614400 | a2 614400
  uint8_t* W1s = (uint8_t*)(ws);
  uint32_t* sbitsT = (uint32_t*)(ws + 1376256);
  float* a1 = (float*)(ws + 1376256 + 3686400);
  uint32_t* sb2 = (uint32_t*)((char*)a1 + (size_t)M_SZ * N_PAD * 4);
  float* a2 = (float*)((char*)sb2 + (size_t)M_SZ * SB2_STRIDE * 4);

  prep<<<dim3(W1_BLOCKS + RNG_BLOCKS), dim3(256), 0, stream>>>(inp, W1, W1s, sbitsT);
  gemm1<<<dim3(MT2, N_PAD / 64), dim3(256), 0, stream>>>(sbitsT, W1s, a1);
  // MEASUREMENT: trio x3 (all idempotent). dur_R17 - dur_R13 = 2*(s+G+P) + ~6.
  scan_spike<<<dim3(N_PAD / 64, B_SZ), dim3(640), 0, stream>>>(a1, sb2);
  scan_spike<<<dim3(N_PAD / 64, B_SZ), dim3(640), 0, stream>>>(a1, sb2);
  scan_spike<<<dim3(N_PAD / 64, B_SZ), dim3(640), 0, stream>>>(a1, sb2);
  gemm2<<<dim3(M_SZ / 4), dim3(256), 0, stream>>>(sb2, W2, a2);
  gemm2<<<dim3(M_SZ / 4), dim3(256), 0, stream>>>(sb2, W2, a2);
  gemm2<<<dim3(M_SZ / 4), dim3(256), 0, stream>>>(sb2, W2, a2);
  psp2<<<dim3(B_SZ), dim3(128), 0, stream>>>(a2, out);
  psp2<<<dim3(B_SZ), dim3(128), 0, stream>>>(a2, out);
  psp2<<<dim3(B_SZ), dim3(128), 0, stream>>>(a2, out);
}

// Round 18
// 157.039 us; speedup vs baseline: 1.2463x; 1.2463x over previous
//
#include <hip/hip_runtime.h>
#include <stdint.h>

#define B_SZ 32
#define T_SZ 300
#define F_IN 3072
#define F_HID 410
#define F_OUT 10
#define M_SZ (B_SZ * T_SZ)              // 9600
#define N_PAD 448                       // a1 row stride = gemm1 N (7 x 64)
#define A2_STRIDE 16
#define SB2_STRIDE 16                   // spike-bit words per m (14 used)
#define NCHUNK 10
#define CLEN 30
#define NKB (F_IN / 256)                // 12 K-blocks of 256
#define MT2 (M_SZ / 128)                // 75 128-row gemm tiles
#define NT32 (N_PAD / 32)               // 14 32-col gemm tiles
#define W1_BLOCKS 672                   // 448*3072/8/256
#define RNG_BLOCKS 14400                // 921600*4/256 (4 threads/word, 8 bits each)

// f32(exp(f32(-0.1))) — PSP decay, matches XLA's correctly-rounded exp
#define DECAY 0.90483741803595957f
#define THETA 10.0f
#define KS2 (0x1BD11BDAu ^ 42u)

typedef __attribute__((ext_vector_type(8))) int i32x8;
typedef __attribute__((ext_vector_type(16))) float f32x16;

// FORCED single-instruction rotate-left, in-place. v_alignbit_b32 x,x,x,(32-r)
// = rotl(r). (R3: prep is at the sustainable VALU issue floor.)
#define TF_R(r) { x0 += x1; \
  asm("v_alignbit_b32 %0, %0, %0, %1" : "+v"(x1) : "n"(32 - (r))); \
  x1 ^= x0; }

// JAX partitionable threefry2x32, key=(0,42), ctr=(0, x1i-42). x0 key-add is 0
// (elided); x1 key-add folded into caller's x1i = base + 42 + jj. Returns o0^o1.
__device__ __forceinline__ uint32_t tf_bits(uint32_t x1i) {
  uint32_t x0 = 0u, x1 = x1i;
  TF_R(13) TF_R(15) TF_R(26) TF_R(6)
  x0 += 42u; x1 += KS2 + 1u;
  TF_R(17) TF_R(29) TF_R(16) TF_R(24)
  x0 += KS2; x1 += 2u;
  TF_R(13) TF_R(15) TF_R(26) TF_R(6)
  x1 += 42u + 3u;
  TF_R(17) TF_R(29) TF_R(16) TF_R(24)
  x0 += 42u; x1 += KS2 + 4u;
  TF_R(13) TF_R(15) TF_R(26) TF_R(6)
  x0 += KS2; x1 += 5u;
  return x0 ^ x1;
}

// async global->LDS, 16 B per lane; LDS dest = wave-uniform base + lane*16
__device__ __forceinline__ void gld16(const void* g, void* l) {
  __builtin_amdgcn_global_load_lds(
      (const __attribute__((address_space(1))) uint32_t*)g,
      (__attribute__((address_space(3))) uint32_t*)l, 16, 0, 0);
}

// R18: MEASURED LEDGER (R16/R17 duplication runs): prep 55.5 | gemm1 19.6 |
// scan+gemm2+psp2 ~17 | gaps ~6 | harness ws-poison ~57 (uncontrollable).
// gemm1 at 19.6 vs ~8 roofline with grid 525 = 2.05 blocks/CU (8 waves/CU):
// occupancy-starved — why R12/R13 inner-loop rewrites were null. This round:
// BN=32 => grid 75x14=1050 (4.1 blocks/CU, 16 waves/CU), same counted-vmcnt
// dbuf pipeline, STAGE = exactly 3 uniform gld16/wave => vmcnt(3).

// Merged prep (R4/R7-verified, unchanged).
__global__ __launch_bounds__(256) void prep(const float* __restrict__ inp,
                                            const float* __restrict__ W1,
                                            uint8_t* __restrict__ W1s,
                                            uint32_t* __restrict__ sbitsT) {
  if (blockIdx.x < W1_BLOCKS) {
    int idx = blockIdx.x * 256 + threadIdx.x;
    int g = idx * 8;
    int n = g / F_IN;
    int k = g - n * F_IN;
    uint32_t d0 = 0u, d1 = 0u;
    if (n < F_HID) {
      const float* s = W1 + (size_t)n * F_IN + k;
      float4 v0 = ((const float4*)s)[0];
      float4 v1 = ((const float4*)s)[1];
      int t0 = __builtin_amdgcn_cvt_pk_fp8_f32(v0.x, v0.y, 0, false);
      t0 = __builtin_amdgcn_cvt_pk_fp8_f32(v0.z, v0.w, t0, true);
      int t1 = __builtin_amdgcn_cvt_pk_fp8_f32(v1.x, v1.y, 0, false);
      t1 = __builtin_amdgcn_cvt_pk_fp8_f32(v1.z, v1.w, t1, true);
      d0 = (uint32_t)t0; d1 = (uint32_t)t1;
    }
    int nt = n >> 6, r = n & 63;
    int kb = k >> 8, c = (k >> 4) & 15, half = (k >> 3) & 1;
    size_t dst = ((((size_t)nt * NKB + kb) * 64 + r) * 16 + (c ^ (r & 15))) * 16 + half * 8;
    *(uint2*)(W1s + dst) = make_uint2(d0, d1);
  } else {
    uint32_t idx = (blockIdx.x - W1_BLOCKS) * 256u + threadIdx.x;  // [0, 3686400)
    uint32_t q = idx & 3u;          // byte within word
    uint32_t j = idx >> 2;          // word index [0, 921600)
    uint32_t r = j & 63u;
    uint32_t t1 = j >> 6;
    uint32_t wi = t1 & 7u;
    uint32_t t2 = t1 >> 3;          // (mt*12 + kb) in [0, 1800)
    uint32_t kb = t2 % (uint32_t)NKB;
    uint32_t mt = t2 / (uint32_t)NKB;
    uint32_t m = mt * 64u + r;      // GEMM row = b*300 + t
    uint32_t b = m / (uint32_t)T_SZ;
    uint32_t f = (kb * 8u + wi) * 32u + q * 8u;
    const float* p = inp + b * F_IN + f;
    float4 va = ((const float4*)p)[0];
    float4 vb = ((const float4*)p)[1];
    uint32_t T0 = (uint32_t)ceilf(va.x * 8388608.0f);
    uint32_t T1 = (uint32_t)ceilf(va.y * 8388608.0f);
    uint32_t T2 = (uint32_t)ceilf(va.z * 8388608.0f);
    uint32_t T3 = (uint32_t)ceilf(va.w * 8388608.0f);
    uint32_t T4 = (uint32_t)ceilf(vb.x * 8388608.0f);
    uint32_t T5 = (uint32_t)ceilf(vb.y * 8388608.0f);
    uint32_t T6 = (uint32_t)ceilf(vb.z * 8388608.0f);
    uint32_t T7 = (uint32_t)ceilf(vb.w * 8388608.0f);
    uint32_t b42 = m * (uint32_t)F_IN + f + 42u;   // counter base + key lo
    uint32_t w = 0u;
#define GEN(jj, Tn) { uint32_t bits = tf_bits(b42 + (jj)); \
  w |= ((bits >> 9) < (Tn)) ? (1u << (jj)) : 0u; }
    GEN(0, T0) GEN(1, T1) GEN(2, T2) GEN(3, T3)
    GEN(4, T4) GEN(5, T5) GEN(6, T6) GEN(7, T7)
#undef GEN
    ((uint8_t*)sbitsT)[idx] = (uint8_t)w;   // byte q of word j: bits [8q, 8q+8)
  }
}

// R18 gemm1: BM=128, BN=32, BK=256, grid 75x14=1050 (4.1 blocks/CU), 4 waves.
// Wave wv owns rows [wv*32, wv*32+32) x cols [0,32): mtile half mh=wv>>1,
// lrow=(wv&1)*32. STAGE = 2x gld16 B-slice (8KB: rows rbase..rbase+31 of the
// 64-row swizzled W1s image — rows contiguous at 256B, swizzle uses r&15 =
// lr&15 since rbase in {0,32}) + 1x gld16 A-half => 3 uniform loads/wave,
// counted vmcnt(3) 2-deep pipeline (R13-verified structure). Accumulation
// order per output element (kb asc, sub asc) unchanged => bit-identical a1.
// LDS 24KB. Nontemporal stores kept.
__global__ __launch_bounds__(256) void gemm1(const uint32_t* __restrict__ sbitsT,
                                             const uint8_t* __restrict__ W1s,
                                             float* __restrict__ a1) {
  __shared__ uint32_t sAT[2][1024];     // [buf][mh*512 + wi*64 + row] 8 KB
  __shared__ uint8_t sB[2][32 * 256];   // [buf] 32-row swizzled slice, 16 KB

  const int tid = threadIdx.x;
  const int bx = blockIdx.x;            // 128-row tile [0,75)
  const int ntt = blockIdx.y;           // 32-col tile [0,14)
  const int m0 = bx * 128;
  const int n0 = ntt * 32;
  const int nt = ntt >> 1;              // 64-row W1s image index
  const int rbase = (ntt & 1) * 32;     // row slice within the image
  const int wv = tid >> 6, lane = tid & 63;
  const int wm = wv * 32;               // wave's row strip in [0,128)
  const int mh = wv >> 1;               // which 64-row mtile
  const int lrow = (wv & 1) * 32;       // strip base within the mtile
  const int l31 = lane & 31, lh = lane >> 5;

  const uint8_t* gA0 = (const uint8_t*)sbitsT + (size_t)(2 * bx) * NKB * 2048;

  auto STAGE = [&](int buf, int kb) {   // exactly 3 gld16 per wave
    const uint8_t* gB = W1s + (((size_t)nt * NKB + kb) * 64 + rbase) * 256;
    gld16(gB + wv * 2048 + lane * 16, &sB[buf][wv * 2048]);
    gld16(gB + wv * 2048 + 1024 + lane * 16, &sB[buf][wv * 2048 + 1024]);
    // A: wave wv stages 1KB = half of mtile (wv>>1)'s kb-block
    gld16(gA0 + (size_t)mh * NKB * 2048 + (size_t)kb * 2048 + (wv & 1) * 1024 + lane * 16,
          (uint8_t*)&sAT[buf][0] + wv * 1024);
  };

  f32x16 acc;
#pragma unroll
  for (int e = 0; e < 16; ++e) acc[e] = 0.0f;

  auto COMPUTE = [&](int buf) {
    const uint8_t* sBc = sB[buf];
    const uint32_t* sATc = &sAT[buf][mh * 512];
#pragma unroll
    for (int sub = 0; sub < 4; ++sub) {
      // B frag: B[n = n0+l31][k = sub*64 + lh*32 + 0..31], local row lr = l31
      int cb = sub * 4 + lh * 2;
      uint4 u0 = *(uint4*)&sBc[l31 * 256 + (((cb + 0) ^ (l31 & 15)) << 4)];
      uint4 u1 = *(uint4*)&sBc[l31 * 256 + (((cb + 1) ^ (l31 & 15)) << 4)];
      i32x8 bfr;
      bfr[0] = u0.x; bfr[1] = u0.y; bfr[2] = u0.z; bfr[3] = u0.w;
      bfr[4] = u1.x; bfr[5] = u1.y; bfr[6] = u1.z; bfr[7] = u1.w;
      // A frag: A[m = wm+l31][same k], expanded bits -> fp8(1.0)=0x38
      uint32_t w = sATc[(sub * 2 + lh) * 64 + lrow + l31];
      i32x8 afr;
#pragma unroll
      for (int j = 0; j < 8; ++j) {
        uint32_t n = (w >> (4 * j)) & 15u;
        afr[j] = (int)(((n * 0x204081u) & 0x01010101u) * 0x38u);
      }
      acc = __builtin_amdgcn_mfma_scale_f32_32x32x64_f8f6f4(
          afr, bfr, acc, 0, 0, 0, 127, 0, 127);
    }
  };

  // 2-deep prologue: tiles 0,1 in flight (6 loads/wave)
  STAGE(0, 0);
  STAGE(1, 1);
  int cur = 0;
  for (int kb = 0; kb < NKB - 1; ++kb) {
    // current tile's 3 loads retired; next tile's 3 stay IN FLIGHT
    asm volatile("s_waitcnt vmcnt(3)" ::: "memory");
    __builtin_amdgcn_s_barrier();
    __builtin_amdgcn_sched_barrier(0);
    COMPUTE(cur);
    __builtin_amdgcn_sched_barrier(0);
    __builtin_amdgcn_s_barrier();      // all waves done reading buf[cur]
    if (kb < NKB - 2) STAGE(cur, kb + 2);
    cur ^= 1;
  }
  asm volatile("s_waitcnt vmcnt(0)" ::: "memory");
  __builtin_amdgcn_s_barrier();
  __builtin_amdgcn_sched_barrier(0);
  COMPUTE(cur);                        // last tile

  // epilogue: C/D 32x32: col = lane&31, row = (reg&3)+8*(reg>>2)+4*(lane>>5)
  int col = n0 + l31;
#pragma unroll
  for (int rg = 0; rg < 16; ++rg) {
    int row = m0 + wm + (rg & 3) + 8 * (rg >> 2) + 4 * lh;
    __builtin_nontemporal_store(acc[rg], &a1[(size_t)row * N_PAD + col]);
  }
}

// R7-verified: psp1 + fscan + threshold merged, no partial materialization.
__global__ __launch_bounds__(640) void scan_spike(const float* __restrict__ a1,
                                                  uint32_t* __restrict__ sb2) {
  __shared__ float fin_s[NCHUNK][64];
  const int oblk = blockIdx.x;          // [0,7)
  const int b = blockIdx.y;             // [0,32)
  const int c = threadIdx.x >> 6;       // chunk = wave id
  const int lane = threadIdx.x & 63;
  const int o = oblk * 64 + lane;
  const float* p = a1 + ((size_t)(b * T_SZ + c * CLEN)) * N_PAD + o;
  float pa[CLEN];
  float u = 0.0f;
#pragma unroll
  for (int i = 0; i < CLEN; ++i) {
    u = __fadd_rn(__fmul_rn(DECAY, u), p[(size_t)i * N_PAD]);
    pa[i] = u;
  }
  fin_s[c][lane] = u;
  __syncthreads();
  float d30 = 1.0f;
#pragma unroll
  for (int i = 0; i < CLEN; ++i) d30 *= DECAY;
  float F = 0.0f;
  for (int cc = 0; cc < c; ++cc)        // fscan's exact chain: F = v + d30*F
    F = fin_s[cc][lane] + d30 * F;
  float dp = DECAY;                     // DECAY^(tl+1), ag2's exact sequence
  const int m0 = b * T_SZ + c * CLEN;
#pragma unroll
  for (int i = 0; i < CLEN; ++i) {
    float uu = (c > 0) ? __fadd_rn(pa[i], __fmul_rn(dp, F)) : pa[i];
    unsigned long long msk = __ballot(uu >= THETA);
    if (lane == 0)
      *(uint2*)&sb2[(size_t)(m0 + i) * SB2_STRIDE + oblk * 2] =
          make_uint2((uint32_t)msk, (uint32_t)(msk >> 32));
    dp *= DECAY;
  }
}

// R7-verified: layer-2 GEMM from spike bits.
__global__ __launch_bounds__(256) void gemm2(const uint32_t* __restrict__ sb2,
                                             const float* __restrict__ W2,
                                             float* __restrict__ a2) {
  __shared__ float sW2[F_OUT * F_HID];   // 16.4 KB
  for (int i = threadIdx.x; i < F_OUT * F_HID; i += 256) sW2[i] = W2[i];
  __syncthreads();
  int m = blockIdx.x * 4 + (threadIdx.x >> 6);
  int lane = threadIdx.x & 63;
  int lh = lane >> 5;
  float p[F_OUT];
#pragma unroll
  for (int o = 0; o < F_OUT; ++o) p[o] = 0.0f;
#pragma unroll
  for (int j = 0; j < 7; ++j) {
    int hh = lane + j * 64;
    uint32_t w = sb2[(size_t)m * SB2_STRIDE + j * 2 + lh];
    float s = (float)((w >> (lane & 31)) & 1u);   // 0 for hh>=F_HID by construction
    int hcl = hh < F_HID ? hh : 0;
#pragma unroll
    for (int o = 0; o < F_OUT; ++o) p[o] = fmaf(s, sW2[o * F_HID + hcl], p[o]);
  }
#pragma unroll
  for (int o = 0; o < F_OUT; ++o)
#pragma unroll
    for (int s = 1; s < 64; s <<= 1) p[o] += __shfl_xor(p[o], s, 64);
  if (lane < F_OUT) a2[(size_t)m * A2_STRIDE + lane] = p[lane];
}

// Layer-2 PSP, chunked, one block per batch; lanes (o,c) in [10x10].
__global__ __launch_bounds__(128) void psp2(const float* __restrict__ a2,
                                            float* __restrict__ out) {
  __shared__ float chf[NCHUNK][F_OUT];
  __shared__ float seed[NCHUNK][F_OUT];
  int b = blockIdx.x;
  int tid = threadIdx.x;
  int o = tid / NCHUNK, c = tid % NCHUNK;
  const float* p = a2 + ((size_t)(b * T_SZ + c * CLEN)) * A2_STRIDE + o;
  float v[CLEN];
  float pa[CLEN];
  if (tid < F_OUT * NCHUNK) {
#pragma unroll
    for (int i = 0; i < CLEN; ++i) v[i] = p[(size_t)i * A2_STRIDE];
    float u = 0.0f;
#pragma unroll
    for (int i = 0; i < CLEN; ++i) {
      u = __fadd_rn(__fmul_rn(DECAY, u), v[i]);
      pa[i] = u;
    }
    chf[c][o] = u;
  }
  __syncthreads();
  if (tid < F_OUT) {
    float d30 = 1.0f;
#pragma unroll
    for (int i = 0; i < CLEN; ++i) d30 *= DECAY;
    float F = 0.0f;
    for (int cc = 0; cc < NCHUNK; ++cc) {
      F = chf[cc][tid] + d30 * F;
      seed[cc][tid] = F;
    }
  }
  __syncthreads();
  if (tid < F_OUT * NCHUNK) {
    float F = (c == 0) ? 0.0f : seed[c - 1][o];
    float dp = DECAY;
    float* q = out + (size_t)b * F_OUT * T_SZ + (size_t)o * T_SZ + c * CLEN;
#pragma unroll
    for (int i = 0; i < CLEN; ++i) {
      float u = (c == 0) ? pa[i] : __fadd_rn(pa[i], __fmul_rn(dp, F));
      q[i] = (u >= THETA) ? 1.0f : 0.0f;
      dp *= DECAY;
    }
  }
}

extern "C" void kernel_launch(void* const* d_in, const int* in_sizes, int n_in,
                              void* d_out, int out_size, void* d_ws, size_t ws_size,
                              hipStream_t stream) {
  const float* inp = (const float*)d_in[0];  // [32,3,32,32]
  const float* W1  = (const float*)d_in[1];  // [410,3072]
  const float* W2  = (const float*)d_in[2];  // [10,410]
  float* out = (float*)d_out;                // [32,10,300]
  char* ws = (char*)d_ws;
  // ws: W1s 1376256 | sbitsT 3686400 | a1 17203200 | sb2 614400 | a2 614400
  uint8_t* W1s = (uint8_t*)(ws);
  uint32_t* sbitsT = (uint32_t*)(ws + 1376256);
  float* a1 = (float*)(ws + 1376256 + 3686400);
  uint32_t* sb2 = (uint32_t*)((char*)a1 + (size_t)M_SZ * N_PAD * 4);
  float* a2 = (float*)((char*)sb2 + (size_t)M_SZ * SB2_STRIDE * 4);

  prep<<<dim3(W1_BLOCKS + RNG_BLOCKS), dim3(256), 0, stream>>>(inp, W1, W1s, sbitsT);
  gemm1<<<dim3(MT2, NT32), dim3(256), 0, stream>>>(sbitsT, W1s, a1);
  scan_spike<<<dim3(N_PAD / 64, B_SZ), dim3(640), 0, stream>>>(a1, sb2);
  gemm2<<<dim3(M_SZ / 4), dim3(256), 0, stream>>>(sb2, W2, a2);
  psp2<<<dim3(B_SZ), dim3(128), 0, stream>>>(a2, out);
}

// Round 20
// 154.688 us; speedup vs baseline: 1.2653x; 1.0152x over previous
//
#include <hip/hip_runtime.h>
#include <stdint.h>

#define B_SZ 32
#define T_SZ 300
#define F_IN 3072
#define F_HID 410
#define F_OUT 10
#define M_SZ (B_SZ * T_SZ)              // 9600
#define N_PAD 448                       // a1 row stride = gemm1 N (7 x 64)
#define A2_STRIDE 16
#define SB2_STRIDE 16                   // spike-bit words per m (14 used)
#define NCHUNK 10
#define CLEN 30
#define NKB (F_IN / 256)                // 12 K-blocks of 256
#define MT2 (M_SZ / 128)                // 75 128-row gemm tiles
#define W1_BLOCKS 672                   // 448*3072/8/256
#define RNG_BLOCKS 14400                // 921600*4/256 (4 threads/word, 8 bits each)

// f32(exp(f32(-0.1))) — PSP decay, matches XLA's correctly-rounded exp
#define DECAY 0.90483741803595957f
#define THETA 10.0f
#define KS2 (0x1BD11BDAu ^ 42u)

typedef __attribute__((ext_vector_type(8))) int i32x8;
typedef __attribute__((ext_vector_type(16))) float f32x16;

// FORCED single-instruction rotate-left, in-place. v_alignbit_b32 x,x,x,(32-r)
// = rotl(r). (R3: prep is at the sustainable VALU issue floor.)
#define TF_R(r) { x0 += x1; \
  asm("v_alignbit_b32 %0, %0, %0, %1" : "+v"(x1) : "n"(32 - (r))); \
  x1 ^= x0; }

// JAX partitionable threefry2x32, key=(0,42), ctr=(0, x1i-42). x0 key-add is 0
// (elided); x1 key-add folded into caller's x1i = base + 42 + jj. Returns o0^o1.
__device__ __forceinline__ uint32_t tf_bits(uint32_t x1i) {
  uint32_t x0 = 0u, x1 = x1i;
  TF_R(13) TF_R(15) TF_R(26) TF_R(6)
  x0 += 42u; x1 += KS2 + 1u;
  TF_R(17) TF_R(29) TF_R(16) TF_R(24)
  x0 += KS2; x1 += 2u;
  TF_R(13) TF_R(15) TF_R(26) TF_R(6)
  x1 += 42u + 3u;
  TF_R(17) TF_R(29) TF_R(16) TF_R(24)
  x0 += 42u; x1 += KS2 + 4u;
  TF_R(13) TF_R(15) TF_R(26) TF_R(6)
  x0 += KS2; x1 += 5u;
  return x0 ^ x1;
}

// async global->LDS, 16 B per lane; LDS dest = wave-uniform base + lane*16
__device__ __forceinline__ void gld16(const void* g, void* l) {
  __builtin_amdgcn_global_load_lds(
      (const __attribute__((address_space(1))) uint32_t*)g,
      (__attribute__((address_space(3))) uint32_t*)l, 16, 0, 0);
}

// R20 = RESUBMIT of R13/R19 (session best, 155.40us, absmax 0.0 — R19's
// container failure was infra flakiness: this exact code passed as R13).
// FINAL MEASURED LEDGER (R15 calibration + R16/R17 duplication runs):
//   prep 55.5us  — threefry VALU floor (94-97% VALUBusy; 29.5M bit-exact evals)
//   gemm1 19.6us — structural (3 rewrites null: VALU-expand+MFMA+mem mix)
//   scan+gemm2+psp2 ~17us — at model
//   gaps ~6us (~1us/dispatch)
//   harness ws-poison ~57us inside timed window — uncontrollable

// Merged prep (R4/R7-verified, unchanged).
__global__ __launch_bounds__(256) void prep(const float* __restrict__ inp,
                                            const float* __restrict__ W1,
                                            uint8_t* __restrict__ W1s,
                                            uint32_t* __restrict__ sbitsT) {
  if (blockIdx.x < W1_BLOCKS) {
    int idx = blockIdx.x * 256 + threadIdx.x;
    int g = idx * 8;
    int n = g / F_IN;
    int k = g - n * F_IN;
    uint32_t d0 = 0u, d1 = 0u;
    if (n < F_HID) {
      const float* s = W1 + (size_t)n * F_IN + k;
      float4 v0 = ((const float4*)s)[0];
      float4 v1 = ((const float4*)s)[1];
      int t0 = __builtin_amdgcn_cvt_pk_fp8_f32(v0.x, v0.y, 0, false);
      t0 = __builtin_amdgcn_cvt_pk_fp8_f32(v0.z, v0.w, t0, true);
      int t1 = __builtin_amdgcn_cvt_pk_fp8_f32(v1.x, v1.y, 0, false);
      t1 = __builtin_amdgcn_cvt_pk_fp8_f32(v1.z, v1.w, t1, true);
      d0 = (uint32_t)t0; d1 = (uint32_t)t1;
    }
    int nt = n >> 6, r = n & 63;
    int kb = k >> 8, c = (k >> 4) & 15, half = (k >> 3) & 1;
    size_t dst = ((((size_t)nt * NKB + kb) * 64 + r) * 16 + (c ^ (r & 15))) * 16 + half * 8;
    *(uint2*)(W1s + dst) = make_uint2(d0, d1);
  } else {
    uint32_t idx = (blockIdx.x - W1_BLOCKS) * 256u + threadIdx.x;  // [0, 3686400)
    uint32_t q = idx & 3u;          // byte within word
    uint32_t j = idx >> 2;          // word index [0, 921600)
    uint32_t r = j & 63u;
    uint32_t t1 = j >> 6;
    uint32_t wi = t1 & 7u;
    uint32_t t2 = t1 >> 3;          // (mt*12 + kb) in [0, 1800)
    uint32_t kb = t2 % (uint32_t)NKB;
    uint32_t mt = t2 / (uint32_t)NKB;
    uint32_t m = mt * 64u + r;      // GEMM row = b*300 + t
    uint32_t b = m / (uint32_t)T_SZ;
    uint32_t f = (kb * 8u + wi) * 32u + q * 8u;
    const float* p = inp + b * F_IN + f;
    float4 va = ((const float4*)p)[0];
    float4 vb = ((const float4*)p)[1];
    uint32_t T0 = (uint32_t)ceilf(va.x * 8388608.0f);
    uint32_t T1 = (uint32_t)ceilf(va.y * 8388608.0f);
    uint32_t T2 = (uint32_t)ceilf(va.z * 8388608.0f);
    uint32_t T3 = (uint32_t)ceilf(va.w * 8388608.0f);
    uint32_t T4 = (uint32_t)ceilf(vb.x * 8388608.0f);
    uint32_t T5 = (uint32_t)ceilf(vb.y * 8388608.0f);
    uint32_t T6 = (uint32_t)ceilf(vb.z * 8388608.0f);
    uint32_t T7 = (uint32_t)ceilf(vb.w * 8388608.0f);
    uint32_t b42 = m * (uint32_t)F_IN + f + 42u;   // counter base + key lo
    uint32_t w = 0u;
#define GEN(jj, Tn) { uint32_t bits = tf_bits(b42 + (jj)); \
  w |= ((bits >> 9) < (Tn)) ? (1u << (jj)) : 0u; }
    GEN(0, T0) GEN(1, T1) GEN(2, T2) GEN(3, T3)
    GEN(4, T4) GEN(5, T5) GEN(6, T6) GEN(7, T7)
#undef GEN
    ((uint8_t*)sbitsT)[idx] = (uint8_t)w;   // byte q of word j: bits [8q, 8q+8)
  }
}

// R13 gemm1 (measured 19.6us): BM=128, BN=64, grid 75x7, 4 waves, 2 MFMAs
// per A-expand, nontemporal stores, counted-vmcnt 2-deep pipeline.
__global__ __launch_bounds__(256) void gemm1(const uint32_t* __restrict__ sbitsT,
                                             const uint8_t* __restrict__ W1s,
                                             float* __restrict__ a1) {
  __shared__ uint32_t sAT[2][2][512];   // [buf][64-row half][wi*64+row] 8 KB
  __shared__ uint8_t sB[2][64 * 256];   // [buf] swizzled image, 32 KB

  const int tid = threadIdx.x;
  const int bx = blockIdx.x;            // 128-row tile [0,75)
  const int nt = blockIdx.y;
  const int m0 = bx * 128;
  const int n0 = nt * 64;
  const int wv = tid >> 6, lane = tid & 63;
  const int wm = wv * 32;               // wave's row strip in [0,128)
  const int half = wv >> 1;             // which 64-row mtile
  const int lrow = (wv & 1) * 32;       // strip base within the half
  const int l31 = lane & 31, lh = lane >> 5;

  const uint8_t* gB0 = W1s + (size_t)nt * NKB * 16384;
  const uint8_t* gA0 = (const uint8_t*)sbitsT + (size_t)(2 * bx) * NKB * 2048;

  auto STAGE = [&](int buf, int kb) {   // exactly 5 gld16 per wave
    const uint8_t* gB = gB0 + (size_t)kb * 16384;
#pragma unroll
    for (int q = 0; q < 4; ++q)
      gld16(gB + (wv * 4 + q) * 1024 + lane * 16, &sB[buf][(wv * 4 + q) * 1024]);
    gld16(gA0 + (size_t)half * NKB * 2048 + (size_t)kb * 2048 + (wv & 1) * 1024 + lane * 16,
          (uint8_t*)&sAT[buf][half][0] + (wv & 1) * 1024);
  };

  f32x16 acc0, acc1;
#pragma unroll
  for (int e = 0; e < 16; ++e) { acc0[e] = 0.0f; acc1[e] = 0.0f; }

  auto COMPUTE = [&](int buf) {
    const uint8_t* sBc = sB[buf];
    const uint32_t* sATc = &sAT[buf][half][0];
#pragma unroll
    for (int sub = 0; sub < 4; ++sub) {
      int cb = sub * 4 + lh * 2;
      int r0 = l31, r1 = 32 + l31;
      uint4 a0 = *(uint4*)&sBc[r0 * 256 + (((cb + 0) ^ (r0 & 15)) << 4)];
      uint4 a1v = *(uint4*)&sBc[r0 * 256 + (((cb + 1) ^ (r0 & 15)) << 4)];
      uint4 b0 = *(uint4*)&sBc[r1 * 256 + (((cb + 0) ^ (r1 & 15)) << 4)];
      uint4 b1 = *(uint4*)&sBc[r1 * 256 + (((cb + 1) ^ (r1 & 15)) << 4)];
      i32x8 bfr0, bfr1;
      bfr0[0] = a0.x; bfr0[1] = a0.y; bfr0[2] = a0.z; bfr0[3] = a0.w;
      bfr0[4] = a1v.x; bfr0[5] = a1v.y; bfr0[6] = a1v.z; bfr0[7] = a1v.w;
      bfr1[0] = b0.x; bfr1[1] = b0.y; bfr1[2] = b0.z; bfr1[3] = b0.w;
      bfr1[4] = b1.x; bfr1[5] = b1.y; bfr1[6] = b1.z; bfr1[7] = b1.w;
      uint32_t w = sATc[(sub * 2 + lh) * 64 + lrow + l31];
      i32x8 afr;
#pragma unroll
      for (int j = 0; j < 8; ++j) {
        uint32_t n = (w >> (4 * j)) & 15u;
        afr[j] = (int)(((n * 0x204081u) & 0x01010101u) * 0x38u);
      }
      acc0 = __builtin_amdgcn_mfma_scale_f32_32x32x64_f8f6f4(
          afr, bfr0, acc0, 0, 0, 0, 127, 0, 127);
      acc1 = __builtin_amdgcn_mfma_scale_f32_32x32x64_f8f6f4(
          afr, bfr1, acc1, 0, 0, 0, 127, 0, 127);
    }
  };

  // 2-deep prologue: tiles 0,1 in flight (10 loads/wave)
  STAGE(0, 0);
  STAGE(1, 1);
  int cur = 0;
  for (int kb = 0; kb < NKB - 1; ++kb) {
    asm volatile("s_waitcnt vmcnt(5)" ::: "memory");
    __builtin_amdgcn_s_barrier();
    __builtin_amdgcn_sched_barrier(0);
    COMPUTE(cur);
    __builtin_amdgcn_sched_barrier(0);
    __builtin_amdgcn_s_barrier();      // all waves done reading buf[cur]
    if (kb < NKB - 2) STAGE(cur, kb + 2);
    cur ^= 1;
  }
  asm volatile("s_waitcnt vmcnt(0)" ::: "memory");
  __builtin_amdgcn_s_barrier();
  __builtin_amdgcn_sched_barrier(0);
  COMPUTE(cur);                        // last tile

#pragma unroll
  for (int rg = 0; rg < 16; ++rg) {
    int row = m0 + wm + (rg & 3) + 8 * (rg >> 2) + 4 * lh;
    __builtin_nontemporal_store(acc0[rg], &a1[(size_t)row * N_PAD + n0 + l31]);
    __builtin_nontemporal_store(acc1[rg], &a1[(size_t)row * N_PAD + n0 + 32 + l31]);
  }
}

// R7-verified: psp1 + fscan + threshold merged, no partial materialization.
__global__ __launch_bounds__(640) void scan_spike(const float* __restrict__ a1,
                                                  uint32_t* __restrict__ sb2) {
  __shared__ float fin_s[NCHUNK][64];
  const int oblk = blockIdx.x;          // [0,7)
  const int b = blockIdx.y;             // [0,32)
  const int c = threadIdx.x >> 6;       // chunk = wave id
  const int lane = threadIdx.x & 63;
  const int o = oblk * 64 + lane;
  const float* p = a1 + ((size_t)(b * T_SZ + c * CLEN)) * N_PAD + o;
  float pa[CLEN];
  float u = 0.0f;
#pragma unroll
  for (int i = 0; i < CLEN; ++i) {
    u = __fadd_rn(__fmul_rn(DECAY, u), p[(size_t)i * N_PAD]);
    pa[i] = u;
  }
  fin_s[c][lane] = u;
  __syncthreads();
  float d30 = 1.0f;
#pragma unroll
  for (int i = 0; i < CLEN; ++i) d30 *= DECAY;
  float F = 0.0f;
  for (int cc = 0; cc < c; ++cc)        // fscan's exact chain: F = v + d30*F
    F = fin_s[cc][lane] + d30 * F;
  float dp = DECAY;                     // DECAY^(tl+1), ag2's exact sequence
  const int m0 = b * T_SZ + c * CLEN;
#pragma unroll
  for (int i = 0; i < CLEN; ++i) {
    float uu = (c > 0) ? __fadd_rn(pa[i], __fmul_rn(dp, F)) : pa[i];
    unsigned long long msk = __ballot(uu >= THETA);
    if (lane == 0)
      *(uint2*)&sb2[(size_t)(m0 + i) * SB2_STRIDE + oblk * 2] =
          make_uint2((uint32_t)msk, (uint32_t)(msk >> 32));
    dp *= DECAY;
  }
}

// R7-verified: layer-2 GEMM from spike bits.
__global__ __launch_bounds__(256) void gemm2(const uint32_t* __restrict__ sb2,
                                             const float* __restrict__ W2,
                                             float* __restrict__ a2) {
  __shared__ float sW2[F_OUT * F_HID];   // 16.4 KB
  for (int i = threadIdx.x; i < F_OUT * F_HID; i += 256) sW2[i] = W2[i];
  __syncthreads();
  int m = blockIdx.x * 4 + (threadIdx.x >> 6);
  int lane = threadIdx.x & 63;
  int lh = lane >> 5;
  float p[F_OUT];
#pragma unroll
  for (int o = 0; o < F_OUT; ++o) p[o] = 0.0f;
#pragma unroll
  for (int j = 0; j < 7; ++j) {
    int hh = lane + j * 64;
    uint32_t w = sb2[(size_t)m * SB2_STRIDE + j * 2 + lh];
    float s = (float)((w >> (lane & 31)) & 1u);   // 0 for hh>=F_HID by construction
    int hcl = hh < F_HID ? hh : 0;
#pragma unroll
    for (int o = 0; o < F_OUT; ++o) p[o] = fmaf(s, sW2[o * F_HID + hcl], p[o]);
  }
#pragma unroll
  for (int o = 0; o < F_OUT; ++o)
#pragma unroll
    for (int s = 1; s < 64; s <<= 1) p[o] += __shfl_xor(p[o], s, 64);
  if (lane < F_OUT) a2[(size_t)m * A2_STRIDE + lane] = p[lane];
}

// Layer-2 PSP, chunked, one block per batch; lanes (o,c) in [10x10].
__global__ __launch_bounds__(128) void psp2(const float* __restrict__ a2,
                                            float* __restrict__ out) {
  __shared__ float chf[NCHUNK][F_OUT];
  __shared__ float seed[NCHUNK][F_OUT];
  int b = blockIdx.x;
  int tid = threadIdx.x;
  int o = tid / NCHUNK, c = tid % NCHUNK;
  const float* p = a2 + ((size_t)(b * T_SZ + c * CLEN)) * A2_STRIDE + o;
  float v[CLEN];
  float pa[CLEN];
  if (tid < F_OUT * NCHUNK) {
#pragma unroll
    for (int i = 0; i < CLEN; ++i) v[i] = p[(size_t)i * A2_STRIDE];
    float u = 0.0f;
#pragma unroll
    for (int i = 0; i < CLEN; ++i) {
      u = __fadd_rn(__fmul_rn(DECAY, u), v[i]);
      pa[i] = u;
    }
    chf[c][o] = u;
  }
  __syncthreads();
  if (tid < F_OUT) {
    float d30 = 1.0f;
#pragma unroll
    for (int i = 0; i < CLEN; ++i) d30 *= DECAY;
    float F = 0.0f;
    for (int cc = 0; cc < NCHUNK; ++cc) {
      F = chf[cc][tid] + d30 * F;
      seed[cc][tid] = F;
    }
  }
  __syncthreads();
  if (tid < F_OUT * NCHUNK) {
    float F = (c == 0) ? 0.0f : seed[c - 1][o];
    float dp = DECAY;
    float* q = out + (size_t)b * F_OUT * T_SZ + (size_t)o * T_SZ + c * CLEN;
#pragma unroll
    for (int i = 0; i < CLEN; ++i) {
      float u = (c == 0) ? pa[i] : __fadd_rn(pa[i], __fmul_rn(dp, F));
      q[i] = (u >= THETA) ? 1.0f : 0.0f;
      dp *= DECAY;
    }
  }
}

extern "C" void kernel_launch(void* const* d_in, const int* in_sizes, int n_in,
                              void* d_out, int out_size, void* d_ws, size_t ws_size,
                              hipStream_t stream) {
  const float* inp = (const float*)d_in[0];  // [32,3,32,32]
  const float* W1  = (const float*)d_in[1];  // [410,3072]
  const float* W2  = (const float*)d_in[2];  // [10,410]
  float* out = (float*)d_out;                // [32,10,300]
  char* ws = (char*)d_ws;
  // ws: W1s 1376256 | sbitsT 3686400 | a1 17203200 | sb2 614400 | a2 614400
  uint8_t* W1s = (uint8_t*)(ws);
  uint32_t* sbitsT = (uint32_t*)(ws + 1376256);
  float* a1 = (float*)(ws + 1376256 + 3686400);
  uint32_t* sb2 = (uint32_t*)((char*)a1 + (size_t)M_SZ * N_PAD * 4);
  float* a2 = (float*)((char*)sb2 + (size_t)M_SZ * SB2_STRIDE * 4);

  prep<<<dim3(W1_BLOCKS + RNG_BLOCKS), dim3(256), 0, stream>>>(inp, W1, W1s, sbitsT);
  gemm1<<<dim3(MT2, N_PAD / 64), dim3(256), 0, stream>>>(sbitsT, W1s, a1);
  scan_spike<<<dim3(N_PAD / 64, B_SZ), dim3(640), 0, stream>>>(a1, sb2);
  gemm2<<<dim3(M_SZ / 4), dim3(256), 0, stream>>>(sb2, W2, a2);
  psp2<<<dim3(B_SZ), dim3(128), 0, stream>>>(a2, out);
}